// Round 6
// baseline (206.643 us; speedup 1.0000x reference)
//
#include <hip/hip_runtime.h>

// GRU fused, MI355X/gfx950 — round 6.
// Config: (256,1), MB=64, grid=256 -> 1 block/CU, 4 waves/CU, 32 cells/lane.
// Rationale: cells/lane x waves/CU is conserved (=128); this corner trades TLP
// for ILP under a 512-reg/wave budget (NO spill possible: weights 120 + frags
// 40 + hm 32 + accs 32 + misc ~250 regs). 16 independent MFMA chains per step.
// Loop uses r5's verified pieces: transposed MFMA (D=[unit][batch], b64 h
// writeback), zero-C trick, bias folded into x pad row k=28. x staged per-step
// (r2-style prefetch — r5's all-t prologue was the regression source).
// All ds_reads hoisted before all ds_writes each step; one barrier per step.

#define B_  16384
#define T_  28
#define F_  28
#define H_  128
#define C_  10
#define MB  64     // batch rows per block
#define LHS 132    // lh row stride in ushorts (264 B; dword-stride 66 -> n*2 mod 32: 16-way spread)
#define LXS 36     // lx row stride in ushorts (72 B; dword-stride 18 -> 16-way spread)

typedef short  short8 __attribute__((ext_vector_type(8)));
typedef float  f32x4  __attribute__((ext_vector_type(4)));

__device__ __forceinline__ unsigned short f2bf(float f) {   // RNE fp32->bf16
    unsigned u = __builtin_bit_cast(unsigned, f);
    u += 0x7fffu + ((u >> 16) & 1u);
    return (unsigned short)(u >> 16);
}
__device__ __forceinline__ float bf2f(unsigned short h) {
    unsigned u = ((unsigned)h) << 16;
    return __builtin_bit_cast(float, u);
}
// pack two fp32 -> two bf16 in one dword (round-half-up + v_perm)
__device__ __forceinline__ unsigned pack_bf16(float lo, float hi) {
    unsigned a = __builtin_bit_cast(unsigned, lo) + 0x8000u;
    unsigned b = __builtin_bit_cast(unsigned, hi) + 0x8000u;
    return __builtin_amdgcn_perm(b, a, 0x07060302u);  // {b[31:16], a[31:16]}
}
__device__ __forceinline__ float fast_sig(float x) {
    float e = __builtin_amdgcn_exp2f(x * -1.442695040888963f);
    return __builtin_amdgcn_rcpf(1.0f + e);
}
__device__ __forceinline__ float fast_tanh(float x) {
    float e = __builtin_amdgcn_exp2f(x * 2.885390081777927f);
    return 1.0f - 2.0f * __builtin_amdgcn_rcpf(1.0f + e);
}

__global__ __launch_bounds__(256, 1)
void gru_fused(const float* __restrict__ x,     // (B,T,F)
               const float* __restrict__ wk,    // (F,3H)
               const float* __restrict__ wrk,   // (H,3H)
               const float* __restrict__ bias,  // (2,3H)
               const float* __restrict__ dw,    // (H,C)
               const float* __restrict__ db,    // (C,)
               float* __restrict__ out)         // (B,C)
{
    // ---- LDS (~78 KB, 1 block/CU so plenty) ----
    __shared__ __align__(16) unsigned short lh[2][MB*LHS];  // h bf16, double-buffered
    __shared__ __align__(16) unsigned short lx[2][MB*LXS];  // x_t bf16, double-buffered
    __shared__ float llog[MB][C_];

    const int tid  = threadIdx.x;
    const int base = blockIdx.x * MB;
    const int lane = tid & 63;
    const int wc   = tid >> 6;    // wave 0..3 -> unit slice [wc*32, wc*32+32)
    const int n    = lane & 15;
    const int q    = lane >> 4;

    // ---- loop-invariant weights -> registers (A-operand frags, 120 VGPR) ----
    // frag elem(lane,j) = W[k = kb*32 + q*8 + j][unit u = wc*32 + ut*16 + n]
    short8 wz[2][4], wr[2][4], wh[2][4];
    short8 xz[2], xr[2], xh[2];            // kernel (K 28->32; row 28 = bias)
    #pragma unroll
    for (int ut = 0; ut < 2; ++ut) {
        const int uw = wc*32 + ut*16 + n;
        #pragma unroll
        for (int kb = 0; kb < 4; ++kb) {
            const int k0 = kb*32 + q*8;
            short8 vz, vr, vh;
            #pragma unroll
            for (int j = 0; j < 8; ++j) {
                const float* wp = wrk + (size_t)(k0 + j)*384 + uw;
                vz[j] = (short)f2bf(wp[0]);
                vr[j] = (short)f2bf(wp[128]);
                vh[j] = (short)f2bf(wp[256]);
            }
            wz[ut][kb] = vz; wr[ut][kb] = vr; wh[ut][kb] = vh;
        }
        short8 vz, vr, vh;
        #pragma unroll
        for (int j = 0; j < 8; ++j) {
            const int k = q*8 + j;
            if (k < F_) {
                const float* wp = wk + (size_t)k*384 + uw;
                vz[j] = (short)f2bf(wp[0]);
                vr[j] = (short)f2bf(wp[128]);
                vh[j] = (short)f2bf(wp[256]);
            } else if (k == F_) {   // bias row (x[28] = 1.0)
                vz[j] = (short)f2bf(bias[uw]       + bias[384 + uw]);
                vr[j] = (short)f2bf(bias[128 + uw] + bias[512 + uw]);
                vh[j] = (short)f2bf(bias[256 + uw]);   // input-side h bias only
            } else { vz[j] = 0; vr[j] = 0; vh[j] = 0; }
        }
        xz[ut] = vz; xr[ut] = vr; xh[ut] = vh;
    }
    // recurrent h-gate bias for this lane's D cells (u = wc*32 + ut*16 + q*4 + reg)
    float brh[2][4];
    #pragma unroll
    for (int ut = 0; ut < 2; ++ut)
        #pragma unroll
        for (int reg = 0; reg < 4; ++reg)
            brh[ut][reg] = bias[640 + wc*32 + ut*16 + q*4 + reg];

    // ---- h0 = 0 ----
    for (int i = tid; i < MB*LHS/2; i += 256) ((unsigned*)lh[0])[i] = 0u;
    // ---- stage x_0: thread i in [0,512): row=i>>3, seg=i&7 (seg 7 = bias row) ----
    #pragma unroll
    for (int it = 0; it < 2; ++it) {
        const int i = tid + it*256;
        const int row = i >> 3, seg = i & 7;
        unsigned p0, p1;
        if (seg < 7) {
            float4 a = *(const float4*)(x + (size_t)(base + row)*(T_*F_) + seg*4);
            p0 = pack_bf16(a.x, a.y); p1 = pack_bf16(a.z, a.w);
        } else { p0 = 0x3F80u; p1 = 0u; }   // k28=1.0, k29..31=0
        *(uint2*)&lx[0][row*LXS + seg*4] = make_uint2(p0, p1);
    }

    float hm[4][2][4];   // fp32 h master [jt][ut][reg]; cell (batch=jt*16+n, u=wc*32+ut*16+q*4+reg)
    #pragma unroll
    for (int jt = 0; jt < 4; ++jt)
        #pragma unroll
        for (int ut = 0; ut < 2; ++ut)
            #pragma unroll
            for (int r = 0; r < 4; ++r) hm[jt][ut][r] = 0.f;

    const f32x4 zero4 = (f32x4){0.f, 0.f, 0.f, 0.f};
    int cur = 0;
    for (int t = 0; t < T_; ++t) {
        __syncthreads();   // step t-1 writes (into cur) visible

        // ---- ALL ds_reads up front (before any ds_write): 20 b128, 40 VGPR ----
        short8 hb[4][4], xb[4];
        #pragma unroll
        for (int jt = 0; jt < 4; ++jt) {
            const int mrow = jt*16 + n;
            #pragma unroll
            for (int kb = 0; kb < 4; ++kb)
                hb[jt][kb] = *(const short8*)&lh[cur][mrow*LHS + kb*32 + q*8];
            xb[jt] = *(const short8*)&lx[t & 1][mrow*LXS + q*8];
        }
        // ---- global prefetch of x_{t+1} (consumed at end of step) ----
        unsigned pf[2][2];
        const bool pv = (t + 1 < T_);
        #pragma unroll
        for (int it = 0; it < 2; ++it) {
            const int i = tid + it*256;
            const int row = i >> 3, seg = i & 7;
            if (pv && seg < 7) {
                float4 a = *(const float4*)(x + (size_t)(base + row)*(T_*F_) + (t+1)*F_ + seg*4);
                pf[it][0] = pack_bf16(a.x, a.y); pf[it][1] = pack_bf16(a.z, a.w);
            } else { pf[it][0] = 0x3F80u; pf[it][1] = 0u; }
        }

        // ---- compute: 4 jt-groups x 2 ut x {15 MFMA + 16-cell gates} ----
        #pragma unroll
        for (int jt = 0; jt < 4; ++jt) {
            const int mrow = jt*16 + n;
            #pragma unroll
            for (int ut = 0; ut < 2; ++ut) {
                f32x4 az = __builtin_amdgcn_mfma_f32_16x16x32_bf16(xz[ut], xb[jt], zero4, 0,0,0);
                f32x4 ar = __builtin_amdgcn_mfma_f32_16x16x32_bf16(xr[ut], xb[jt], zero4, 0,0,0);
                f32x4 ax = __builtin_amdgcn_mfma_f32_16x16x32_bf16(xh[ut], xb[jt], zero4, 0,0,0);
                f32x4 ah = __builtin_amdgcn_mfma_f32_16x16x32_bf16(wh[ut][0], hb[jt][0], zero4, 0,0,0);
                #pragma unroll
                for (int kb = 0; kb < 4; ++kb) {
                    az = __builtin_amdgcn_mfma_f32_16x16x32_bf16(wz[ut][kb], hb[jt][kb], az, 0,0,0);
                    ar = __builtin_amdgcn_mfma_f32_16x16x32_bf16(wr[ut][kb], hb[jt][kb], ar, 0,0,0);
                    if (kb) ah = __builtin_amdgcn_mfma_f32_16x16x32_bf16(wh[ut][kb], hb[jt][kb], ah, 0,0,0);
                }
                float hn[4];
                #pragma unroll
                for (int reg = 0; reg < 4; ++reg) {
                    float z  = fast_sig(az[reg]);
                    float r  = fast_sig(ar[reg]);
                    float hh = fast_tanh(ax[reg] + r * (ah[reg] + brh[ut][reg]));
                    float hv = hh + z * (hm[jt][ut][reg] - hh);
                    hm[jt][ut][reg] = hv;
                    hn[reg] = hv;
                }
                uint2 p;
                p.x = pack_bf16(hn[0], hn[1]);
                p.y = pack_bf16(hn[2], hn[3]);
                *(uint2*)&lh[cur ^ 1][mrow*LHS + wc*32 + ut*16 + q*4] = p;
            }
        }
        // ---- commit prefetched x into lx[(t+1)&1] ----
        if (pv) {
            #pragma unroll
            for (int it = 0; it < 2; ++it) {
                const int i = tid + it*256;
                const int row = i >> 3, seg = i & 7;
                *(uint2*)&lx[(t+1)&1][row*LXS + seg*4] = make_uint2(pf[it][0], pf[it][1]);
            }
        }
        cur ^= 1;
    }

    // ---- dense + softmax epilogue (final h in lh[cur]) ----
    __syncthreads();
    {
        const int row = tid >> 2, qq = tid & 3;
        for (int c = qq; c < C_; c += 4) {
            float s = db[c];
            #pragma unroll
            for (int u0 = 0; u0 < H_; u0 += 8) {
                short8 hv = *(const short8*)&lh[cur][row*LHS + u0];
                #pragma unroll
                for (int j = 0; j < 8; ++j)
                    s += bf2f((unsigned short)hv[j]) * dw[(u0+j)*C_ + c];
            }
            llog[row][c] = s;
        }
    }
    __syncthreads();
    if (tid < MB) {
        const int row = tid;
        float m = llog[row][0];
        #pragma unroll
        for (int c = 1; c < C_; ++c) m = fmaxf(m, llog[row][c]);
        float e[C_], s = 0.f;
        #pragma unroll
        for (int c = 0; c < C_; ++c) {
            e[c] = __builtin_amdgcn_exp2f((llog[row][c] - m) * 1.442695040888963f);
            s += e[c];
        }
        const float inv = __builtin_amdgcn_rcpf(s);
        float* o = out + (size_t)(base + row)*C_;
        #pragma unroll
        for (int c = 0; c < C_; ++c) o[c] = e[c] * inv;
    }
}

extern "C" void kernel_launch(void* const* d_in, const int* in_sizes, int n_in,
                              void* d_out, int out_size, void* d_ws, size_t ws_size,
                              hipStream_t stream) {
    const float* x   = (const float*)d_in[0];
    const float* wk  = (const float*)d_in[1];
    const float* wrk = (const float*)d_in[2];
    const float* bs  = (const float*)d_in[3];
    const float* dw  = (const float*)d_in[4];
    const float* db  = (const float*)d_in[5];
    (void)in_sizes; (void)n_in; (void)out_size; (void)d_ws; (void)ws_size;
    gru_fused<<<dim3(B_/MB), dim3(256), 0, stream>>>(x, wk, wrk, bs, dw, db, (float*)d_out);
}

// Round 7
// 185.486 us; speedup vs baseline: 1.1141x; 1.1141x over previous
//
#include <hip/hip_runtime.h>

// GRU fused, MI355X/gfx950 — round 7.
// = r2's proven shape + r5/r6's verified lean loop (never combined before):
//   shape: (256,2), MB=32, grid=512 -> 2 blocks/CU, 8 waves/CU, 2 waves/SIMD
//   loop: transposed MFMA (D=[unit][batch]), zero-C accumulator start,
//         bias folded into x pad row k=28, v_perm bf16 pack + b64 h writeback,
//         LHS=132/LXS=36 strides (r6: conflicts 3.9M -> 0.23M)
//   x: per-step register prefetch (r2-style; r5's all-t prologue was the bug)
// Reg audit: weights 120 + hm 16 + brh 8 + pf 2 + addr ~10 + transients ~30
//            ~= 190 arch + 16 acc < 256 cap -> no spill.

#define B_  16384
#define T_  28
#define F_  28
#define H_  128
#define C_  10
#define MB  32     // batch rows per block
#define LHS 132    // lh row stride in ushorts
#define LXS 36     // lx row stride in ushorts

typedef short  short8 __attribute__((ext_vector_type(8)));
typedef float  f32x4  __attribute__((ext_vector_type(4)));

__device__ __forceinline__ unsigned short f2bf(float f) {   // RNE fp32->bf16
    unsigned u = __builtin_bit_cast(unsigned, f);
    u += 0x7fffu + ((u >> 16) & 1u);
    return (unsigned short)(u >> 16);
}
__device__ __forceinline__ float bf2f(unsigned short h) {
    unsigned u = ((unsigned)h) << 16;
    return __builtin_bit_cast(float, u);
}
// pack two fp32 -> two bf16 in one dword (round-half-up + v_perm)
__device__ __forceinline__ unsigned pack_bf16(float lo, float hi) {
    unsigned a = __builtin_bit_cast(unsigned, lo) + 0x8000u;
    unsigned b = __builtin_bit_cast(unsigned, hi) + 0x8000u;
    return __builtin_amdgcn_perm(b, a, 0x07060302u);  // {b[31:16], a[31:16]}
}
__device__ __forceinline__ float fast_sig(float x) {
    float e = __builtin_amdgcn_exp2f(x * -1.442695040888963f);
    return __builtin_amdgcn_rcpf(1.0f + e);
}
__device__ __forceinline__ float fast_tanh(float x) {
    float e = __builtin_amdgcn_exp2f(x * 2.885390081777927f);
    return 1.0f - 2.0f * __builtin_amdgcn_rcpf(1.0f + e);
}

__global__ __launch_bounds__(256, 2)
void gru_fused(const float* __restrict__ x,     // (B,T,F)
               const float* __restrict__ wk,    // (F,3H)
               const float* __restrict__ wrk,   // (H,3H)
               const float* __restrict__ bias,  // (2,3H)
               const float* __restrict__ dw,    // (H,C)
               const float* __restrict__ db,    // (C,)
               float* __restrict__ out)         // (B,C)
{
    // ---- LDS (~22 KB; 2 blocks/CU = 44 KB) ----
    __shared__ __align__(16) unsigned short lh[2][MB*LHS];  // h bf16, double-buffered
    __shared__ __align__(16) unsigned short lx[2][MB*LXS];  // x_t bf16, double-buffered
    __shared__ float llog[MB][C_];

    const int tid  = threadIdx.x;
    const int base = blockIdx.x * MB;
    const int lane = tid & 63;
    const int wc   = tid >> 6;    // wave 0..3 -> unit slice [wc*32, wc*32+32)
    const int n    = lane & 15;
    const int q    = lane >> 4;

    // ---- loop-invariant weights -> registers (A-operand frags, 120 VGPR) ----
    // frag elem(lane,j) = W[k = kb*32 + q*8 + j][unit u = wc*32 + ut*16 + n]
    short8 wz[2][4], wr[2][4], wh[2][4];
    short8 xz[2], xr[2], xh[2];            // kernel (K 28->32; row 28 = bias)
    #pragma unroll
    for (int ut = 0; ut < 2; ++ut) {
        const int uw = wc*32 + ut*16 + n;
        #pragma unroll
        for (int kb = 0; kb < 4; ++kb) {
            const int k0 = kb*32 + q*8;
            short8 vz, vr, vh;
            #pragma unroll
            for (int j = 0; j < 8; ++j) {
                const float* wp = wrk + (size_t)(k0 + j)*384 + uw;
                vz[j] = (short)f2bf(wp[0]);
                vr[j] = (short)f2bf(wp[128]);
                vh[j] = (short)f2bf(wp[256]);
            }
            wz[ut][kb] = vz; wr[ut][kb] = vr; wh[ut][kb] = vh;
        }
        short8 vz, vr, vh;
        #pragma unroll
        for (int j = 0; j < 8; ++j) {
            const int k = q*8 + j;
            if (k < F_) {
                const float* wp = wk + (size_t)k*384 + uw;
                vz[j] = (short)f2bf(wp[0]);
                vr[j] = (short)f2bf(wp[128]);
                vh[j] = (short)f2bf(wp[256]);
            } else if (k == F_) {   // bias row (x[28] = 1.0)
                vz[j] = (short)f2bf(bias[uw]       + bias[384 + uw]);
                vr[j] = (short)f2bf(bias[128 + uw] + bias[512 + uw]);
                vh[j] = (short)f2bf(bias[256 + uw]);   // input-side h bias only
            } else { vz[j] = 0; vr[j] = 0; vh[j] = 0; }
        }
        xz[ut] = vz; xr[ut] = vr; xh[ut] = vh;
    }
    // recurrent h-gate bias for this lane's D cells (u = wc*32 + ut*16 + q*4 + reg)
    float brh[2][4];
    #pragma unroll
    for (int ut = 0; ut < 2; ++ut)
        #pragma unroll
        for (int reg = 0; reg < 4; ++reg)
            brh[ut][reg] = bias[640 + wc*32 + ut*16 + q*4 + reg];

    // ---- h0 = 0 ----
    for (int i = tid; i < MB*LHS/2; i += 256) ((unsigned*)lh[0])[i] = 0u;
    // ---- stage x_0: thread = (row 0..31, seg 0..7); seg 7 = bias pad ----
    {
        const int row = tid >> 3, seg = tid & 7;
        unsigned p0, p1;
        if (seg < 7) {
            float4 a = *(const float4*)(x + (size_t)(base + row)*(T_*F_) + seg*4);
            p0 = pack_bf16(a.x, a.y); p1 = pack_bf16(a.z, a.w);
        } else { p0 = 0x3F80u; p1 = 0u; }   // k28=1.0, k29..31=0
        *(uint2*)&lx[0][row*LXS + seg*4] = make_uint2(p0, p1);
    }

    float hm[2][2][4];   // fp32 h master [jt][ut][reg]; cell (batch=jt*16+n? no: batch=jt*16+col n of D) 
    #pragma unroll
    for (int jt = 0; jt < 2; ++jt)
        #pragma unroll
        for (int ut = 0; ut < 2; ++ut)
            #pragma unroll
            for (int r = 0; r < 4; ++r) hm[jt][ut][r] = 0.f;

    const f32x4 zero4 = (f32x4){0.f, 0.f, 0.f, 0.f};
    int cur = 0;
    for (int t = 0; t < T_; ++t) {
        __syncthreads();   // step t-1 writes (into cur) visible

        // ---- ALL ds_reads up front (before any ds_write): 10 b128 ----
        short8 hb[2][4], xb[2];
        #pragma unroll
        for (int jt = 0; jt < 2; ++jt) {
            const int mrow = jt*16 + n;
            #pragma unroll
            for (int kb = 0; kb < 4; ++kb)
                hb[jt][kb] = *(const short8*)&lh[cur][mrow*LHS + kb*32 + q*8];
            xb[jt] = *(const short8*)&lx[t & 1][mrow*LXS + q*8];
        }
        // ---- global prefetch of x_{t+1} ----
        unsigned pf0 = 0x3F80u, pf1 = 0u;
        const int prow = tid >> 3, pseg = tid & 7;
        const bool pv = (t + 1 < T_);
        if (pv && pseg < 7) {
            float4 a = *(const float4*)(x + (size_t)(base + prow)*(T_*F_) + (t+1)*F_ + pseg*4);
            pf0 = pack_bf16(a.x, a.y); pf1 = pack_bf16(a.z, a.w);
        }

        // ---- compute: 2 jt x 2 ut x {15 MFMA + 16-cell gates} ----
        #pragma unroll
        for (int jt = 0; jt < 2; ++jt) {
            const int mrow = jt*16 + n;
            #pragma unroll
            for (int ut = 0; ut < 2; ++ut) {
                f32x4 az = __builtin_amdgcn_mfma_f32_16x16x32_bf16(xz[ut], xb[jt], zero4, 0,0,0);
                f32x4 ar = __builtin_amdgcn_mfma_f32_16x16x32_bf16(xr[ut], xb[jt], zero4, 0,0,0);
                f32x4 ax = __builtin_amdgcn_mfma_f32_16x16x32_bf16(xh[ut], xb[jt], zero4, 0,0,0);
                f32x4 ah = __builtin_amdgcn_mfma_f32_16x16x32_bf16(wh[ut][0], hb[jt][0], zero4, 0,0,0);
                #pragma unroll
                for (int kb = 0; kb < 4; ++kb) {
                    az = __builtin_amdgcn_mfma_f32_16x16x32_bf16(wz[ut][kb], hb[jt][kb], az, 0,0,0);
                    ar = __builtin_amdgcn_mfma_f32_16x16x32_bf16(wr[ut][kb], hb[jt][kb], ar, 0,0,0);
                    if (kb) ah = __builtin_amdgcn_mfma_f32_16x16x32_bf16(wh[ut][kb], hb[jt][kb], ah, 0,0,0);
                }
                // gates; D (transposed): row q*4+reg = unit, col n = batch
                float hn[4];
                #pragma unroll
                for (int reg = 0; reg < 4; ++reg) {
                    float z  = fast_sig(az[reg]);
                    float r  = fast_sig(ar[reg]);
                    float hh = fast_tanh(ax[reg] + r * (ah[reg] + brh[ut][reg]));
                    float hv = hh + z * (hm[jt][ut][reg] - hh);
                    hm[jt][ut][reg] = hv;
                    hn[reg] = hv;
                }
                uint2 p;
                p.x = pack_bf16(hn[0], hn[1]);
                p.y = pack_bf16(hn[2], hn[3]);
                *(uint2*)&lh[cur ^ 1][mrow*LHS + wc*32 + ut*16 + q*4] = p;
            }
        }
        // ---- commit prefetched x ----
        if (pv)
            *(uint2*)&lx[(t+1)&1][prow*LXS + pseg*4] = make_uint2(pf0, pf1);
        cur ^= 1;
    }

    // ---- dense + softmax epilogue (final h in lh[cur]) ----
    __syncthreads();
    if (tid < 128) {
        const int row = tid >> 2, qq = tid & 3;
        for (int c = qq; c < C_; c += 4) {
            float s = db[c];
            #pragma unroll
            for (int u0 = 0; u0 < H_; u0 += 8) {
                short8 hv = *(const short8*)&lh[cur][row*LHS + u0];
                #pragma unroll
                for (int j = 0; j < 8; ++j)
                    s += bf2f((unsigned short)hv[j]) * dw[(u0+j)*C_ + c];
            }
            llog[row][c] = s;
        }
    }
    __syncthreads();
    if (tid < MB) {
        const int row = tid;
        float m = llog[row][0];
        #pragma unroll
        for (int c = 1; c < C_; ++c) m = fmaxf(m, llog[row][c]);
        float e[C_], s = 0.f;
        #pragma unroll
        for (int c = 0; c < C_; ++c) {
            e[c] = __builtin_amdgcn_exp2f((llog[row][c] - m) * 1.442695040888963f);
            s += e[c];
        }
        const float inv = __builtin_amdgcn_rcpf(s);
        float* o = out + (size_t)(base + row)*C_;
        #pragma unroll
        for (int c = 0; c < C_; ++c) o[c] = e[c] * inv;
    }
}

extern "C" void kernel_launch(void* const* d_in, const int* in_sizes, int n_in,
                              void* d_out, int out_size, void* d_ws, size_t ws_size,
                              hipStream_t stream) {
    const float* x   = (const float*)d_in[0];
    const float* wk  = (const float*)d_in[1];
    const float* wrk = (const float*)d_in[2];
    const float* bs  = (const float*)d_in[3];
    const float* dw  = (const float*)d_in[4];
    const float* db  = (const float*)d_in[5];
    (void)in_sizes; (void)n_in; (void)out_size; (void)d_ws; (void)ws_size;
    gru_fused<<<dim3(B_/MB), dim3(256), 0, stream>>>(x, wk, wrk, bs, dw, db, (float*)d_out);
}